// Round 3
// baseline (145.737 us; speedup 1.0000x reference)
//
#include <hip/hip_runtime.h>

#define N_DIM 4096

typedef float f4  __attribute__((ext_vector_type(4)));
typedef short s8v __attribute__((ext_vector_type(8)));

// fp32 -> bf16 RNE. Prefer HW packed convert if the builtin exists.
#if defined(__has_builtin)
#if __has_builtin(__builtin_amdgcn_cvt_pk_bf16_f32)
#define HAVE_CVT_PK 1
#endif
#endif

static __device__ __forceinline__ unsigned int f2bf_pair(float lo, float hi) {
#ifdef HAVE_CVT_PK
    typedef __bf16 bf2 __attribute__((ext_vector_type(2)));
    bf2 p = __builtin_amdgcn_cvt_pk_bf16_f32(lo, hi);
    return __builtin_bit_cast(unsigned int, p);
#else
    unsigned int ul = __builtin_bit_cast(unsigned int, lo);
    unsigned int uh = __builtin_bit_cast(unsigned int, hi);
    ul = ul + 0x7fffu + ((ul >> 16) & 1u);
    uh = uh + 0x7fffu + ((uh >> 16) & 1u);
    return (uh & 0xffff0000u) | (ul >> 16);
#endif
}

// 8 consecutive fp32 (two f4) -> one bf16x8 MFMA fragment
static __device__ __forceinline__ s8v cvt8(f4 a, f4 b) {
    unsigned int r0 = f2bf_pair(a[0], a[1]);
    unsigned int r1 = f2bf_pair(a[2], a[3]);
    unsigned int r2 = f2bf_pair(b[0], b[1]);
    unsigned int r3 = f2bf_pair(b[2], b[3]);
    unsigned int u4[4] = {r0, r1, r2, r3};
    return __builtin_bit_cast(s8v, u4);
}

__global__ void zero_out_kernel(float* __restrict__ out) {
    if (threadIdx.x == 0 && blockIdx.x == 0) out[0] = 0.f;
}

// One block per 16-row i-tile. NO LDS, NO barriers in the K-loop: for
// mfma_16x16x32_bf16 both fragments are 8 CONSECUTIVE row elements
// (A[m=lane&15][k=(lane>>4)*8+j] — verified in-situ R2, absmax 0.0), so
// fragments load straight from global as two dwordx4 at immediate offsets.
// One-chunk register prefetch: 16 loads x 1 KB in flight per wave keeps the
// per-CU HBM share saturated; vmcnt stalls overlap with memory delivery.
__global__ __launch_bounds__(256) void fused_kernel(
    const float* __restrict__ zs, const float* __restrict__ X,
    const float* __restrict__ varp, float* __restrict__ out) {
    const int tid  = threadIdx.x;
    const int lane = tid & 63;
    const int w    = tid >> 6;            // wave w owns k-slice [16w, 16w+16)
    const int i0   = blockIdx.x * 16;
    const int coff = (lane >> 4) * 8;     // per-lane column sub-offset

    const float* pz = zs + (size_t)(16 * w + (lane & 15)) * N_DIM + coff;
    const float* px = X  + (size_t)(i0   + (lane & 15)) * N_DIM + coff;

    f4 acc = {0.f, 0.f, 0.f, 0.f};
    f4 za[8], xb[8];

    // preload chunk 0: fragment s covers columns s*32 + coff + [0,8)
    #pragma unroll
    for (int s = 0; s < 4; ++s) {
        za[2 * s]     = *(const f4*)(pz + s * 32);
        za[2 * s + 1] = *(const f4*)(pz + s * 32 + 4);
        xb[2 * s]     = *(const f4*)(px + s * 32);
        xb[2 * s + 1] = *(const f4*)(px + s * 32 + 4);
    }

    for (int c = 0; c < 32; ++c) {
        // convert current chunk's raw fp32 into MFMA fragments
        s8v af[4], bf[4];
        #pragma unroll
        for (int s = 0; s < 4; ++s) {
            af[s] = cvt8(za[2 * s], za[2 * s + 1]);
            bf[s] = cvt8(xb[2 * s], xb[2 * s + 1]);
        }
        // issue next chunk's 16 loads (SSA-renamed; in flight across MFMAs)
        if (c < 31) {
            const float* qz = pz + (c + 1) * 128;
            const float* qx = px + (c + 1) * 128;
            #pragma unroll
            for (int s = 0; s < 4; ++s) {
                za[2 * s]     = *(const f4*)(qz + s * 32);
                za[2 * s + 1] = *(const f4*)(qz + s * 32 + 4);
                xb[2 * s]     = *(const f4*)(qx + s * 32);
                xb[2 * s + 1] = *(const f4*)(qx + s * 32 + 4);
            }
        }
        #pragma unroll
        for (int s = 0; s < 4; ++s)
            acc = __builtin_amdgcn_mfma_f32_16x16x32_bf16(af[s], bf[s], acc, 0, 0, 0);
    }

    // Epilogue (verified R2). C/D layout: col = lane&15 (i), row = (lane>>4)*4 + r (k)
    const int   i_g  = i0 + (lane & 15);
    const float diag = X[(size_t)i_g * N_DIM + i_g];
    const float var  = varp[0];
    float lsum = 0.f;
    #pragma unroll
    for (int r = 0; r < 4; ++r) {
        int   k   = 16 * w + ((lane >> 4) << 2) + r;
        float num = zs[(size_t)k * N_DIM + i_g] * diag;   // exact fp32
        float den = acc[r] - num;
        lsum += num / (var + den);
    }
    #pragma unroll
    for (int off = 32; off >= 1; off >>= 1) lsum += __shfl_down(lsum, off);
    __shared__ float wsum[4];
    if (lane == 0) wsum[w] = lsum;
    __syncthreads();
    if (tid == 0)
        atomicAdd(out, -(wsum[0] + wsum[1] + wsum[2] + wsum[3]) * (1.0f / 64.0f));
}

extern "C" void kernel_launch(void* const* d_in, const int* in_sizes, int n_in,
                              void* d_out, int out_size, void* d_ws, size_t ws_size,
                              hipStream_t stream) {
    const float* zs   = (const float*)d_in[0];
    const float* X    = (const float*)d_in[1];
    const float* varp = (const float*)d_in[2];
    float* out = (float*)d_out;

    hipLaunchKernelGGL(zero_out_kernel, dim3(1), dim3(64), 0, stream, out);
    hipLaunchKernelGGL(fused_kernel, dim3(256), dim3(256), 0, stream, zs, X, varp, out);
}